// Round 7
// baseline (890.070 us; speedup 1.0000x reference)
//
#include <hip/hip_runtime.h>
#include <hip/hip_bf16.h>

#define N_NODES 50000
#define N_EDGES 800000
#define HID 128
#define SCAN_BLK 512
#define N_SCAN_BLOCKS ((N_NODES + SCAN_BLK - 1) / SCAN_BLK)  // 98

typedef __attribute__((ext_vector_type(8))) short bf16x8;
typedef __attribute__((ext_vector_type(4))) float f32x4;

__device__ __forceinline__ ushort f2bf(float f) {
    uint u = __float_as_uint(f);
    return (ushort)((u + 0x7FFFu + ((u >> 16) & 1u)) >> 16);  // RNE
}
__device__ __forceinline__ float bf2f(ushort h) { return __uint_as_float(((uint)h) << 16); }

// ---------------- CSR build ----------------
__global__ void k_zero_cnt(int* cnt) {
    int i = blockIdx.x * blockDim.x + threadIdx.x;
    if (i < N_NODES) cnt[i] = 0;
}

__global__ void k_count(const int* __restrict__ ei, int* cnt) {
    int e = blockIdx.x * blockDim.x + threadIdx.x;
    if (e < N_EDGES) atomicAdd(&cnt[ei[N_EDGES + e]], 1);
}

__global__ __launch_bounds__(SCAN_BLK) void k_scan1(const int* __restrict__ cnt,
                                                    int* __restrict__ rowStart,
                                                    int* __restrict__ blockSums,
                                                    float* __restrict__ dinv) {
    __shared__ int tmp[SCAN_BLK];
    int i = blockIdx.x * SCAN_BLK + threadIdx.x;
    int v = (i < N_NODES) ? cnt[i] : 0;
    if (i < N_NODES) dinv[i] = rsqrtf(1.0f + (float)v);
    tmp[threadIdx.x] = v;
    __syncthreads();
    for (int off = 1; off < SCAN_BLK; off <<= 1) {
        int t = (threadIdx.x >= off) ? tmp[threadIdx.x - off] : 0;
        __syncthreads();
        tmp[threadIdx.x] += t;
        __syncthreads();
    }
    if (i < N_NODES) rowStart[i] = tmp[threadIdx.x] - v;  // exclusive
    if (threadIdx.x == SCAN_BLK - 1) blockSums[blockIdx.x] = tmp[SCAN_BLK - 1];
}

__global__ void k_scan2(int* blockSums) {
    if (blockIdx.x == 0 && threadIdx.x == 0) {
        int acc = 0;
        for (int i = 0; i < N_SCAN_BLOCKS; ++i) {
            int t = blockSums[i];
            blockSums[i] = acc;
            acc += t;
        }
    }
}

__global__ __launch_bounds__(SCAN_BLK) void k_scan3(int* __restrict__ rowStart,
                                                    const int* __restrict__ blockSums,
                                                    int* __restrict__ cursor) {
    int i = blockIdx.x * SCAN_BLK + threadIdx.x;
    if (i < N_NODES) {
        rowStart[i] += blockSums[blockIdx.x];
        cursor[i] = 0;
    }
    if (i == 0) rowStart[N_NODES] = N_EDGES;
}

// csrA[pos] = src ; csrE[pos] = {src, edge_id}
__global__ void k_fill(const int* __restrict__ ei, const int* __restrict__ rowStart,
                       int* cursor, int* __restrict__ csrA, int2* __restrict__ csrE) {
    int e = blockIdx.x * blockDim.x + threadIdx.x;
    if (e < N_EDGES) {
        int s = ei[e];
        int d = ei[N_EDGES + e];
        int pos = rowStart[d] + atomicAdd(&cursor[d], 1);
        csrA[pos] = s;
        csrE[pos] = make_int2(s, e);
    }
}

// ---------------- 5x weight transpose + bf16 hi/lo split: T[j][k] = split(W[k][j]) ----------------
struct WSplitArgs {
    const float* src[5];
    ushort* th[5];
    ushort* tl[5];
};

__global__ void k_tsplit5(WSplitArgs a) {
    int i = blockIdx.x * 256 + threadIdx.x;  // 5 * 16384
    int which = i >> 14, r = i & 16383;
    int k = r >> 7, j = r & 127;
    float v = a.src[which][r];
    ushort hi = f2bf(v);
    a.th[which][j * 128 + k] = hi;
    a.tl[which][j * 128 + k] = f2bf(v - bf2f(hi));
}

// ---------------- encoder: h0 = relu(x @ W_enc + b), stored as bf16 hi/lo split ----------------
__global__ void k_encoder(const float* __restrict__ x, const float* __restrict__ W,
                          const float* __restrict__ b, ushort* __restrict__ hH,
                          ushort* __restrict__ hL) {
    int i = blockIdx.x * 256 + threadIdx.x;  // N*64 threads, 2 cols each
    int n = i >> 6, l = i & 63;
    int j = l * 2;
    float4 xv = *(const float4*)(x + (size_t)n * 4);
    float2 acc = *(const float2*)(b + j);
    float2 w0 = *(const float2*)(W + 0 * 128 + j);
    float2 w1 = *(const float2*)(W + 1 * 128 + j);
    float2 w2 = *(const float2*)(W + 2 * 128 + j);
    float2 w3 = *(const float2*)(W + 3 * 128 + j);
    acc.x += xv.x * w0.x + xv.y * w1.x + xv.z * w2.x + xv.w * w3.x;
    acc.y += xv.x * w0.y + xv.y * w1.y + xv.z * w2.y + xv.w * w3.y;
    float v0 = fmaxf(acc.x, 0.f), v1 = fmaxf(acc.y, 0.f);
    ushort h0 = f2bf(v0), h1 = f2bf(v1);
    ushort l0 = f2bf(v0 - bf2f(h0)), l1 = f2bf(v1 - bf2f(h1));
    ((uint*)hH)[i] = (uint)h0 | ((uint)h1 << 16);
    ((uint*)hL)[i] = (uint)l0 | ((uint)l1 << 16);
}

// ---------------- MFMA GEMM body: out[M,128] = A @ BT^T (+bias) (*scale) ----------------
// Swapped operands: mfma(W_frag, h_frag) -> D col = node (lane&15), row = j -> float4 stores.
__device__ __forceinline__ void gemm_body(const ushort* __restrict__ AH,
                                          const ushort* __restrict__ AL,
                                          const ushort* __restrict__ BTH,
                                          const ushort* __restrict__ BTL,
                                          float* __restrict__ out,
                                          const float* __restrict__ bias,
                                          const float* __restrict__ scale, int M) {
    int tid = threadIdx.x;
    int w = tid >> 6, l = tid & 63;
    int ln = l & 15, lk = l >> 4;
    int r0 = blockIdx.x * 128 + w * 32;      // wave covers 32 rows (2 node-tiles)
    int row0 = r0 + ln, row1 = r0 + 16 + ln;
    int a0 = row0 < M ? row0 : M - 1;
    int a1 = row1 < M ? row1 : M - 1;

    f32x4 acc0[8] = {};
    f32x4 acc1[8] = {};
#pragma unroll
    for (int kc = 0; kc < 4; ++kc) {
        int ko = kc * 32 + lk * 8;
        bf16x8 h0H = *(const bf16x8*)(AH + (size_t)a0 * 128 + ko);
        bf16x8 h0L = *(const bf16x8*)(AL + (size_t)a0 * 128 + ko);
        bf16x8 h1H = *(const bf16x8*)(AH + (size_t)a1 * 128 + ko);
        bf16x8 h1L = *(const bf16x8*)(AL + (size_t)a1 * 128 + ko);
#pragma unroll
        for (int nt = 0; nt < 8; ++nt) {
            size_t boff = (size_t)(nt * 16 + ln) * 128 + ko;
            bf16x8 wH = *(const bf16x8*)(BTH + boff);
            bf16x8 wL = *(const bf16x8*)(BTL + boff);
            acc0[nt] = __builtin_amdgcn_mfma_f32_16x16x32_bf16(wH, h0H, acc0[nt], 0, 0, 0);
            acc0[nt] = __builtin_amdgcn_mfma_f32_16x16x32_bf16(wL, h0H, acc0[nt], 0, 0, 0);
            acc0[nt] = __builtin_amdgcn_mfma_f32_16x16x32_bf16(wH, h0L, acc0[nt], 0, 0, 0);
            acc1[nt] = __builtin_amdgcn_mfma_f32_16x16x32_bf16(wH, h1H, acc1[nt], 0, 0, 0);
            acc1[nt] = __builtin_amdgcn_mfma_f32_16x16x32_bf16(wL, h1H, acc1[nt], 0, 0, 0);
            acc1[nt] = __builtin_amdgcn_mfma_f32_16x16x32_bf16(wH, h1L, acc1[nt], 0, 0, 0);
        }
    }
    float s0v = scale ? scale[a0] : 1.f;
    float s1v = scale ? scale[a1] : 1.f;
#pragma unroll
    for (int nt = 0; nt < 8; ++nt) {
        int jb = nt * 16 + lk * 4;
        float4 bv;
        if (bias) bv = *(const float4*)(bias + jb);
        else bv = make_float4(0.f, 0.f, 0.f, 0.f);
        if (row0 < M) {
            float4 o = make_float4((acc0[nt][0] + bv.x) * s0v, (acc0[nt][1] + bv.y) * s0v,
                                   (acc0[nt][2] + bv.z) * s0v, (acc0[nt][3] + bv.w) * s0v);
            *(float4*)(out + (size_t)row0 * 128 + jb) = o;
        }
        if (row1 < M) {
            float4 o = make_float4((acc1[nt][0] + bv.x) * s1v, (acc1[nt][1] + bv.y) * s1v,
                                   (acc1[nt][2] + bv.z) * s1v, (acc1[nt][3] + bv.w) * s1v);
            *(float4*)(out + (size_t)row1 * 128 + jb) = o;
        }
    }
}

__global__ __launch_bounds__(256) void k_gemm_mfma(const ushort* __restrict__ AH,
                                                   const ushort* __restrict__ AL,
                                                   const ushort* __restrict__ BTH,
                                                   const ushort* __restrict__ BTL,
                                                   float* __restrict__ out,
                                                   const float* __restrict__ scale, int M) {
    gemm_body(AH, AL, BTH, BTL, out, nullptr, scale, M);
}

// P and Q in one dispatch: blockIdx.y selects weight/output set.
__global__ __launch_bounds__(256) void k_gemm_pq(const ushort* __restrict__ AH,
                                                 const ushort* __restrict__ AL,
                                                 const ushort* __restrict__ BTHt,
                                                 const ushort* __restrict__ BTLt,
                                                 const ushort* __restrict__ BTHb,
                                                 const ushort* __restrict__ BTLb,
                                                 float* __restrict__ outP,
                                                 float* __restrict__ outQ,
                                                 const float* __restrict__ b1, int M) {
    if (blockIdx.y == 0)
        gemm_body(AH, AL, BTHt, BTLt, outP, nullptr, nullptr, M);
    else
        gemm_body(AH, AL, BTHb, BTLb, outQ, b1, nullptr, M);
}

// ---------------- sliced aggregate: h = relu(b + dinv[n]*(hw'[n] + sum hw'[src])) ----------------
// Column-sliced for XCD L2 residency: slice = blockIdx & 7 (blocks round-robin XCDs),
// so XCD s only touches hw columns [s*16, s*16+16) -> 3.2 MB, L2-resident.
// Wave per (node, slice): 4 groups x 16 lanes, 4 edges in flight, 1-ahead pipeline.
__global__ __launch_bounds__(256) void k_aggregate(const float* __restrict__ hw,
                                                   const float* __restrict__ b,
                                                   const float* __restrict__ dinv,
                                                   const int* __restrict__ rowStart,
                                                   const int* __restrict__ csrA,
                                                   ushort* __restrict__ hH,
                                                   ushort* __restrict__ hL) {
    int bid = blockIdx.x;
    int slice = bid & 7;
    int n = (bid >> 3) * 4 + (threadIdx.x >> 6);
    if (n >= N_NODES) return;
    int l = threadIdx.x & 63;
    int g = l >> 4, li = l & 15;
    int col = slice * 16 + li;

    float acc = (g == 0) ? hw[(size_t)n * 128 + col] : 0.f;  // self term
    int s0 = rowStart[n], s1 = rowStart[n + 1];
    int k = s0 + g;
    float v = 0.f;
    if (k < s1) {
        int src = csrA[k];
        v = hw[(size_t)src * 128 + col];
    }
    for (; k < s1; k += 4) {
        float vn = 0.f;
        int kn = k + 4;
        if (kn < s1) {
            int srcn = csrA[kn];
            vn = hw[(size_t)srcn * 128 + col];
        }
        acc += v;
        v = vn;
    }
    // combine the 4 groups (same col set in each group)
    acc += __shfl_xor(acc, 32);
    acc += __shfl_xor(acc, 16);
    if (g == 0) {
        float di = dinv[n];
        float val = fmaxf(b[col] + di * acc, 0.f);
        ushort hi = f2bf(val);
        hH[(size_t)n * 128 + col] = hi;
        hL[(size_t)n * 128 + col] = f2bf(val - bf2f(hi));
    }
}

// ---------------- edge final: out[eid] = relu(P[src] + Qb[dst]) @ W2 + b2 ----------------
// One wave per dst node; Qb (= Q + b1) in registers. 4 groups of 16 lanes process
// 4 edges concurrently, software-pipelined one edge ahead.
__global__ __launch_bounds__(256) void k_edge_final(const float* __restrict__ P,
                                                    const float* __restrict__ Qb,
                                                    const int* __restrict__ rowStart,
                                                    const int2* __restrict__ csrE,
                                                    const float* __restrict__ W2,
                                                    const float* __restrict__ b2,
                                                    float* __restrict__ out) {
    int wid = (blockIdx.x * 256 + threadIdx.x) >> 6;  // one wave per dst node
    int l = threadIdx.x & 63;
    if (wid >= N_NODES) return;
    int s0 = rowStart[wid], s1 = rowStart[wid + 1];
    if (s0 >= s1) return;
    int j8 = (l & 15) * 8;  // my 8 columns
    int g = l >> 4;         // edge-slot within wave

    float4 qa = *(const float4*)(Qb + (size_t)wid * 128 + j8);
    float4 qb = *(const float4*)(Qb + (size_t)wid * 128 + j8 + 4);
    float w2r[8][3];
#pragma unroll
    for (int k = 0; k < 8; ++k) {
        w2r[k][0] = W2[(j8 + k) * 3 + 0];
        w2r[k][1] = W2[(j8 + k) * 3 + 1];
        w2r[k][2] = W2[(j8 + k) * 3 + 2];
    }
    float bz0 = b2[0], bz1 = b2[1], bz2 = b2[2];

    int k = s0 + g;
    int2 c = make_int2(0, 0);
    float4 pa = make_float4(0.f, 0.f, 0.f, 0.f), pb = pa;
    if (k < s1) {
        c = csrE[k];
        const float* pr = P + (size_t)c.x * 128 + j8;
        pa = *(const float4*)(pr);
        pb = *(const float4*)(pr + 4);
    }
    for (; k < s1; k += 4) {
        int kn = k + 4;
        int2 cn = make_int2(0, 0);
        float4 pan = make_float4(0.f, 0.f, 0.f, 0.f), pbn = pan;
        if (kn < s1) {
            cn = csrE[kn];
            const float* prn = P + (size_t)cn.x * 128 + j8;
            pan = *(const float4*)(prn);
            pbn = *(const float4*)(prn + 4);
        }
        float z[8];
        z[0] = fmaxf(pa.x + qa.x, 0.f);
        z[1] = fmaxf(pa.y + qa.y, 0.f);
        z[2] = fmaxf(pa.z + qa.z, 0.f);
        z[3] = fmaxf(pa.w + qa.w, 0.f);
        z[4] = fmaxf(pb.x + qb.x, 0.f);
        z[5] = fmaxf(pb.y + qb.y, 0.f);
        z[6] = fmaxf(pb.z + qb.z, 0.f);
        z[7] = fmaxf(pb.w + qb.w, 0.f);
        float o0 = 0.f, o1 = 0.f, o2 = 0.f;
#pragma unroll
        for (int q = 0; q < 8; ++q) {
            o0 += z[q] * w2r[q][0];
            o1 += z[q] * w2r[q][1];
            o2 += z[q] * w2r[q][2];
        }
#pragma unroll
        for (int m = 1; m < 16; m <<= 1) {  // reduce within 16-lane group
            o0 += __shfl_xor(o0, m);
            o1 += __shfl_xor(o1, m);
            o2 += __shfl_xor(o2, m);
        }
        if ((l & 15) == 0) {
            float* op = out + (size_t)c.y * 3;
            op[0] = o0 + bz0;
            op[1] = o1 + bz1;
            op[2] = o2 + bz2;
        }
        c = cn;
        pa = pan;
        pb = pbn;
    }
}

extern "C" void kernel_launch(void* const* d_in, const int* in_sizes, int n_in,
                              void* d_out, int out_size, void* d_ws, size_t ws_size,
                              hipStream_t stream) {
    const float* x     = (const float*)d_in[0];
    const int*   ei    = (const int*)d_in[1];
    const float* W_enc = (const float*)d_in[2];
    const float* b_enc = (const float*)d_in[3];
    const float* Wg[3] = {(const float*)d_in[4], (const float*)d_in[6], (const float*)d_in[8]};
    const float* bg[3] = {(const float*)d_in[5], (const float*)d_in[7], (const float*)d_in[9]};
    const float* W_m1  = (const float*)d_in[10];
    const float* b_m1  = (const float*)d_in[11];
    const float* W_m2  = (const float*)d_in[12];
    const float* b_m2  = (const float*)d_in[13];
    float* out = (float*)d_out;

    // workspace layout (~87 MB)
    char* w = (char*)d_ws;
    ushort* hH      = (ushort*)w;  w += (size_t)N_NODES * HID * 2;       // 12.8 MB
    ushort* hL      = (ushort*)w;  w += (size_t)N_NODES * HID * 2;       // 12.8 MB
    float*  hB      = (float*)w;   w += (size_t)N_NODES * HID * 4;       // 25.6 MB (hw' / P)
    float*  Qb      = (float*)w;   w += (size_t)N_NODES * HID * 4;       // 25.6 MB (Q + b1)
    int2*   csrE    = (int2*)w;    w += (size_t)N_EDGES * 8;             // 6.4 MB
    int*    csrA    = (int*)w;     w += (size_t)N_EDGES * 4;             // 3.2 MB
    float*  dinv    = (float*)w;   w += (size_t)N_NODES * 4;
    int*    rowStart= (int*)w;     w += (size_t)(N_NODES + 4) * 4;
    int*    cursor  = (int*)w;     w += (size_t)N_NODES * 4;
    int*    blockSums=(int*)w;     w += 512;
    ushort* WgTH[3], *WgTL[3];
    for (int i = 0; i < 3; ++i) {
        WgTH[i] = (ushort*)w; w += 128 * 128 * 2;
        WgTL[i] = (ushort*)w; w += 128 * 128 * 2;
    }
    ushort* WtTH = (ushort*)w; w += 128 * 128 * 2;
    ushort* WtTL = (ushort*)w; w += 128 * 128 * 2;
    ushort* WbTH = (ushort*)w; w += 128 * 128 * 2;
    ushort* WbTL = (ushort*)w; w += 128 * 128 * 2;

    // --- CSR build (once; reused across layers + edge stage) ---
    k_zero_cnt<<<(N_NODES + 255) / 256, 256, 0, stream>>>(cursor);
    k_count<<<(N_EDGES + 255) / 256, 256, 0, stream>>>(ei, cursor);
    k_scan1<<<N_SCAN_BLOCKS, SCAN_BLK, 0, stream>>>(cursor, rowStart, blockSums, dinv);
    k_scan2<<<1, 64, 0, stream>>>(blockSums);
    k_scan3<<<N_SCAN_BLOCKS, SCAN_BLK, 0, stream>>>(rowStart, blockSums, cursor);
    k_fill<<<(N_EDGES + 255) / 256, 256, 0, stream>>>(ei, rowStart, cursor, csrA, csrE);

    // --- all 5 weight transpose+splits in one launch ---
    WSplitArgs wa;
    wa.src[0] = Wg[0]; wa.th[0] = WgTH[0]; wa.tl[0] = WgTL[0];
    wa.src[1] = Wg[1]; wa.th[1] = WgTH[1]; wa.tl[1] = WgTL[1];
    wa.src[2] = Wg[2]; wa.th[2] = WgTH[2]; wa.tl[2] = WgTL[2];
    wa.src[3] = W_m1;             wa.th[3] = WtTH; wa.tl[3] = WtTL;
    wa.src[4] = W_m1 + 128 * 128; wa.th[4] = WbTH; wa.tl[4] = WbTL;
    k_tsplit5<<<5 * 16384 / 256, 256, 0, stream>>>(wa);

    k_encoder<<<N_NODES * 64 / 256, 256, 0, stream>>>(x, W_enc, b_enc, hH, hL);

    const int gemmGrid = (N_NODES + 127) / 128;
    const int aggGrid = ((N_NODES + 3) / 4) * 8;  // (node-quads) x 8 slices
    for (int l = 0; l < 3; ++l) {
        // hw' = (relu(h) @ Wg) * dinv[row]
        k_gemm_mfma<<<gemmGrid, 256, 0, stream>>>(hH, hL, WgTH[l], WgTL[l], hB, dinv, N_NODES);
        k_aggregate<<<aggGrid, 256, 0, stream>>>(hB, bg[l], dinv, rowStart, csrA, hH, hL);
    }

    // P = relu(h3)@W1_top ; Qb = relu(h3)@W1_bot + b1  (one dispatch, blockIdx.y)
    dim3 pqGrid(gemmGrid, 2);
    k_gemm_pq<<<pqGrid, 256, 0, stream>>>(hH, hL, WtTH, WtTL, WbTH, WbTL, hB, Qb, b_m1, N_NODES);

    k_edge_final<<<(N_NODES * 64) / 256, 256, 0, stream>>>(hB, Qb, rowStart, csrE, W_m2, b_m2, out);
}

// Round 8
// 505.345 us; speedup vs baseline: 1.7613x; 1.7613x over previous
//
#include <hip/hip_runtime.h>
#include <hip/hip_bf16.h>

#define N_NODES 50000
#define N_EDGES 800000
#define HID 128
#define SCAN_BLK 512
#define N_SCAN_BLOCKS ((N_NODES + SCAN_BLK - 1) / SCAN_BLK)  // 98

typedef __attribute__((ext_vector_type(8))) short bf16x8;
typedef __attribute__((ext_vector_type(4))) float f32x4;

__device__ __forceinline__ ushort f2bf(float f) {
    uint u = __float_as_uint(f);
    return (ushort)((u + 0x7FFFu + ((u >> 16) & 1u)) >> 16);  // RNE
}
__device__ __forceinline__ float bf2f(ushort h) { return __uint_as_float(((uint)h) << 16); }

// ---------------- CSR build ----------------
__global__ void k_zero_cnt(int* cnt) {
    int i = blockIdx.x * blockDim.x + threadIdx.x;
    if (i < N_NODES) cnt[i] = 0;
}

__global__ void k_count(const int* __restrict__ ei, int* cnt) {
    int e = blockIdx.x * blockDim.x + threadIdx.x;
    if (e < N_EDGES) atomicAdd(&cnt[ei[N_EDGES + e]], 1);
}

__global__ __launch_bounds__(SCAN_BLK) void k_scan1(const int* __restrict__ cnt,
                                                    int* __restrict__ rowStart,
                                                    int* __restrict__ blockSums,
                                                    float* __restrict__ dinv) {
    __shared__ int tmp[SCAN_BLK];
    int i = blockIdx.x * SCAN_BLK + threadIdx.x;
    int v = (i < N_NODES) ? cnt[i] : 0;
    if (i < N_NODES) dinv[i] = rsqrtf(1.0f + (float)v);
    tmp[threadIdx.x] = v;
    __syncthreads();
    for (int off = 1; off < SCAN_BLK; off <<= 1) {
        int t = (threadIdx.x >= off) ? tmp[threadIdx.x - off] : 0;
        __syncthreads();
        tmp[threadIdx.x] += t;
        __syncthreads();
    }
    if (i < N_NODES) rowStart[i] = tmp[threadIdx.x] - v;  // exclusive
    if (threadIdx.x == SCAN_BLK - 1) blockSums[blockIdx.x] = tmp[SCAN_BLK - 1];
}

__global__ void k_scan2(int* blockSums) {
    if (blockIdx.x == 0 && threadIdx.x == 0) {
        int acc = 0;
        for (int i = 0; i < N_SCAN_BLOCKS; ++i) {
            int t = blockSums[i];
            blockSums[i] = acc;
            acc += t;
        }
    }
}

__global__ __launch_bounds__(SCAN_BLK) void k_scan3(int* __restrict__ rowStart,
                                                    const int* __restrict__ blockSums,
                                                    int* __restrict__ cursor) {
    int i = blockIdx.x * SCAN_BLK + threadIdx.x;
    if (i < N_NODES) {
        rowStart[i] += blockSums[blockIdx.x];
        cursor[i] = 0;
    }
    if (i == 0) rowStart[N_NODES] = N_EDGES;
}

// csrA[pos] = src ; csrE[pos] = {src, edge_id}
__global__ void k_fill(const int* __restrict__ ei, const int* __restrict__ rowStart,
                       int* cursor, int* __restrict__ csrA, int2* __restrict__ csrE) {
    int e = blockIdx.x * blockDim.x + threadIdx.x;
    if (e < N_EDGES) {
        int s = ei[e];
        int d = ei[N_EDGES + e];
        int pos = rowStart[d] + atomicAdd(&cursor[d], 1);
        csrA[pos] = s;
        csrE[pos] = make_int2(s, e);
    }
}

// ---------------- 5x weight transpose + bf16 hi/lo split: T[j][k] = split(W[k][j]) ----------------
struct WSplitArgs {
    const float* src[5];
    ushort* th[5];
    ushort* tl[5];
};

__global__ void k_tsplit5(WSplitArgs a) {
    int i = blockIdx.x * 256 + threadIdx.x;  // 5 * 16384
    int which = i >> 14, r = i & 16383;
    int k = r >> 7, j = r & 127;
    float v = a.src[which][r];
    ushort hi = f2bf(v);
    a.th[which][j * 128 + k] = hi;
    a.tl[which][j * 128 + k] = f2bf(v - bf2f(hi));
}

// ---------------- encoder: h0 = relu(x @ W_enc + b), stored as bf16 hi/lo split ----------------
__global__ void k_encoder(const float* __restrict__ x, const float* __restrict__ W,
                          const float* __restrict__ b, ushort* __restrict__ hH,
                          ushort* __restrict__ hL) {
    int i = blockIdx.x * 256 + threadIdx.x;  // N*64 threads, 2 cols each
    int n = i >> 6, l = i & 63;
    int j = l * 2;
    float4 xv = *(const float4*)(x + (size_t)n * 4);
    float2 acc = *(const float2*)(b + j);
    float2 w0 = *(const float2*)(W + 0 * 128 + j);
    float2 w1 = *(const float2*)(W + 1 * 128 + j);
    float2 w2 = *(const float2*)(W + 2 * 128 + j);
    float2 w3 = *(const float2*)(W + 3 * 128 + j);
    acc.x += xv.x * w0.x + xv.y * w1.x + xv.z * w2.x + xv.w * w3.x;
    acc.y += xv.x * w0.y + xv.y * w1.y + xv.z * w2.y + xv.w * w3.y;
    float v0 = fmaxf(acc.x, 0.f), v1 = fmaxf(acc.y, 0.f);
    ushort h0 = f2bf(v0), h1 = f2bf(v1);
    ushort l0 = f2bf(v0 - bf2f(h0)), l1 = f2bf(v1 - bf2f(h1));
    ((uint*)hH)[i] = (uint)h0 | ((uint)h1 << 16);
    ((uint*)hL)[i] = (uint)l0 | ((uint)l1 << 16);
}

// ---------------- MFMA GEMM body: out[M,128] = A @ BT^T (+bias) (*scale) ----------------
// Swapped operands: mfma(W_frag, h_frag) -> D col = node (lane&15), row = j -> float4 stores.
__device__ __forceinline__ void gemm_body(const ushort* __restrict__ AH,
                                          const ushort* __restrict__ AL,
                                          const ushort* __restrict__ BTH,
                                          const ushort* __restrict__ BTL,
                                          float* __restrict__ out,
                                          const float* __restrict__ bias,
                                          const float* __restrict__ scale, int M) {
    int tid = threadIdx.x;
    int w = tid >> 6, l = tid & 63;
    int ln = l & 15, lk = l >> 4;
    int r0 = blockIdx.x * 128 + w * 32;      // wave covers 32 rows (2 node-tiles)
    int row0 = r0 + ln, row1 = r0 + 16 + ln;
    int a0 = row0 < M ? row0 : M - 1;
    int a1 = row1 < M ? row1 : M - 1;

    f32x4 acc0[8] = {};
    f32x4 acc1[8] = {};
#pragma unroll
    for (int kc = 0; kc < 4; ++kc) {
        int ko = kc * 32 + lk * 8;
        bf16x8 h0H = *(const bf16x8*)(AH + (size_t)a0 * 128 + ko);
        bf16x8 h0L = *(const bf16x8*)(AL + (size_t)a0 * 128 + ko);
        bf16x8 h1H = *(const bf16x8*)(AH + (size_t)a1 * 128 + ko);
        bf16x8 h1L = *(const bf16x8*)(AL + (size_t)a1 * 128 + ko);
#pragma unroll
        for (int nt = 0; nt < 8; ++nt) {
            size_t boff = (size_t)(nt * 16 + ln) * 128 + ko;
            bf16x8 wH = *(const bf16x8*)(BTH + boff);
            bf16x8 wL = *(const bf16x8*)(BTL + boff);
            acc0[nt] = __builtin_amdgcn_mfma_f32_16x16x32_bf16(wH, h0H, acc0[nt], 0, 0, 0);
            acc0[nt] = __builtin_amdgcn_mfma_f32_16x16x32_bf16(wL, h0H, acc0[nt], 0, 0, 0);
            acc0[nt] = __builtin_amdgcn_mfma_f32_16x16x32_bf16(wH, h0L, acc0[nt], 0, 0, 0);
            acc1[nt] = __builtin_amdgcn_mfma_f32_16x16x32_bf16(wH, h1H, acc1[nt], 0, 0, 0);
            acc1[nt] = __builtin_amdgcn_mfma_f32_16x16x32_bf16(wL, h1H, acc1[nt], 0, 0, 0);
            acc1[nt] = __builtin_amdgcn_mfma_f32_16x16x32_bf16(wH, h1L, acc1[nt], 0, 0, 0);
        }
    }
    float s0v = scale ? scale[a0] : 1.f;
    float s1v = scale ? scale[a1] : 1.f;
#pragma unroll
    for (int nt = 0; nt < 8; ++nt) {
        int jb = nt * 16 + lk * 4;
        float4 bv;
        if (bias) bv = *(const float4*)(bias + jb);
        else bv = make_float4(0.f, 0.f, 0.f, 0.f);
        if (row0 < M) {
            float4 o = make_float4((acc0[nt][0] + bv.x) * s0v, (acc0[nt][1] + bv.y) * s0v,
                                   (acc0[nt][2] + bv.z) * s0v, (acc0[nt][3] + bv.w) * s0v);
            *(float4*)(out + (size_t)row0 * 128 + jb) = o;
        }
        if (row1 < M) {
            float4 o = make_float4((acc1[nt][0] + bv.x) * s1v, (acc1[nt][1] + bv.y) * s1v,
                                   (acc1[nt][2] + bv.z) * s1v, (acc1[nt][3] + bv.w) * s1v);
            *(float4*)(out + (size_t)row1 * 128 + jb) = o;
        }
    }
}

__global__ __launch_bounds__(256) void k_gemm_mfma(const ushort* __restrict__ AH,
                                                   const ushort* __restrict__ AL,
                                                   const ushort* __restrict__ BTH,
                                                   const ushort* __restrict__ BTL,
                                                   float* __restrict__ out,
                                                   const float* __restrict__ scale, int M) {
    gemm_body(AH, AL, BTH, BTL, out, nullptr, scale, M);
}

// P and Q in one dispatch: blockIdx.y selects weight/output set.
__global__ __launch_bounds__(256) void k_gemm_pq(const ushort* __restrict__ AH,
                                                 const ushort* __restrict__ AL,
                                                 const ushort* __restrict__ BTHt,
                                                 const ushort* __restrict__ BTLt,
                                                 const ushort* __restrict__ BTHb,
                                                 const ushort* __restrict__ BTLb,
                                                 float* __restrict__ outP,
                                                 float* __restrict__ outQ,
                                                 const float* __restrict__ b1, int M) {
    if (blockIdx.y == 0)
        gemm_body(AH, AL, BTHt, BTLt, outP, nullptr, nullptr, M);
    else
        gemm_body(AH, AL, BTHb, BTLb, outQ, b1, nullptr, M);
}

// ---------------- aggregate: h = relu(b + dinv[n]*(hw'[n] + sum hw'[src])), bf16-split store ----
// hw' rows pre-scaled by dinv[src]. Two 32-lane groups per wave, each float4/lane
// (one full 512B row per group), software-pipelined TWO edges ahead -> 6 rows in flight.
__global__ __launch_bounds__(256) void k_aggregate(const float* __restrict__ hw,
                                                   const float* __restrict__ b,
                                                   const float* __restrict__ dinv,
                                                   const int* __restrict__ rowStart,
                                                   const int* __restrict__ csrA,
                                                   ushort* __restrict__ hH,
                                                   ushort* __restrict__ hL) {
    int wid = (blockIdx.x * 256 + threadIdx.x) >> 6;  // one wave per node
    int l = threadIdx.x & 63;
    if (wid >= N_NODES) return;
    int half = l >> 5, li = l & 31;
    int c4 = li * 4;

    float4 acc;
    if (half == 0) acc = *(const float4*)(hw + (size_t)wid * 128 + c4);  // self term
    else acc = make_float4(0.f, 0.f, 0.f, 0.f);

    int s0 = rowStart[wid], s1 = rowStart[wid + 1];
    int k = s0 + half;
    float4 v0 = make_float4(0.f, 0.f, 0.f, 0.f), v1 = v0;
    if (k < s1) v0 = *(const float4*)(hw + (size_t)csrA[k] * 128 + c4);
    if (k + 2 < s1) v1 = *(const float4*)(hw + (size_t)csrA[k + 2] * 128 + c4);
    for (; k < s1; k += 2) {
        float4 v2 = make_float4(0.f, 0.f, 0.f, 0.f);
        if (k + 4 < s1) v2 = *(const float4*)(hw + (size_t)csrA[k + 4] * 128 + c4);
        acc.x += v0.x; acc.y += v0.y; acc.z += v0.z; acc.w += v0.w;
        v0 = v1;
        v1 = v2;
    }
    // combine the two edge-groups (same columns, lanes l and l^32)
    acc.x += __shfl_xor(acc.x, 32);
    acc.y += __shfl_xor(acc.y, 32);
    acc.z += __shfl_xor(acc.z, 32);
    acc.w += __shfl_xor(acc.w, 32);

    if (half == 0) {
        float di = dinv[wid];
        float4 bb = *(const float4*)(b + c4);
        float v0f = fmaxf(bb.x + di * acc.x, 0.f);
        float v1f = fmaxf(bb.y + di * acc.y, 0.f);
        float v2f = fmaxf(bb.z + di * acc.z, 0.f);
        float v3f = fmaxf(bb.w + di * acc.w, 0.f);
        ushort h0 = f2bf(v0f), h1 = f2bf(v1f), h2 = f2bf(v2f), h3 = f2bf(v3f);
        uint2 uh = make_uint2((uint)h0 | ((uint)h1 << 16), (uint)h2 | ((uint)h3 << 16));
        ushort l0 = f2bf(v0f - bf2f(h0)), l1 = f2bf(v1f - bf2f(h1));
        ushort l2 = f2bf(v2f - bf2f(h2)), l3 = f2bf(v3f - bf2f(h3));
        uint2 ul = make_uint2((uint)l0 | ((uint)l1 << 16), (uint)l2 | ((uint)l3 << 16));
        *(uint2*)(hH + (size_t)wid * 128 + c4) = uh;
        *(uint2*)(hL + (size_t)wid * 128 + c4) = ul;
    }
}

// ---------------- edge final: out[eid] = relu(P[src] + Qb[dst]) @ W2 + b2 ----------------
// One wave per dst node; Qb (= Q + b1) in registers. 4 groups of 16 lanes process
// 4 edges concurrently, software-pipelined TWO edges ahead -> 12 rows in flight.
__global__ __launch_bounds__(256) void k_edge_final(const float* __restrict__ P,
                                                    const float* __restrict__ Qb,
                                                    const int* __restrict__ rowStart,
                                                    const int2* __restrict__ csrE,
                                                    const float* __restrict__ W2,
                                                    const float* __restrict__ b2,
                                                    float* __restrict__ out) {
    int wid = (blockIdx.x * 256 + threadIdx.x) >> 6;  // one wave per dst node
    int l = threadIdx.x & 63;
    if (wid >= N_NODES) return;
    int s0 = rowStart[wid], s1 = rowStart[wid + 1];
    if (s0 >= s1) return;
    int j8 = (l & 15) * 8;  // my 8 columns
    int g = l >> 4;         // edge-slot within wave

    float4 qa = *(const float4*)(Qb + (size_t)wid * 128 + j8);
    float4 qb = *(const float4*)(Qb + (size_t)wid * 128 + j8 + 4);
    float w2r[8][3];
#pragma unroll
    for (int k = 0; k < 8; ++k) {
        w2r[k][0] = W2[(j8 + k) * 3 + 0];
        w2r[k][1] = W2[(j8 + k) * 3 + 1];
        w2r[k][2] = W2[(j8 + k) * 3 + 2];
    }
    float bz0 = b2[0], bz1 = b2[1], bz2 = b2[2];

    int k = s0 + g;
    int2 c0 = make_int2(0, 0), c1 = c0;
    float4 pa0 = make_float4(0.f, 0.f, 0.f, 0.f), pb0 = pa0, pa1 = pa0, pb1 = pa0;
    if (k < s1) {
        c0 = csrE[k];
        const float* pr = P + (size_t)c0.x * 128 + j8;
        pa0 = *(const float4*)(pr);
        pb0 = *(const float4*)(pr + 4);
    }
    if (k + 4 < s1) {
        c1 = csrE[k + 4];
        const float* pr = P + (size_t)c1.x * 128 + j8;
        pa1 = *(const float4*)(pr);
        pb1 = *(const float4*)(pr + 4);
    }
    for (; k < s1; k += 4) {
        int kn = k + 8;
        int2 c2 = make_int2(0, 0);
        float4 pa2 = make_float4(0.f, 0.f, 0.f, 0.f), pb2 = pa2;
        if (kn < s1) {
            c2 = csrE[kn];
            const float* prn = P + (size_t)c2.x * 128 + j8;
            pa2 = *(const float4*)(prn);
            pb2 = *(const float4*)(prn + 4);
        }
        float z[8];
        z[0] = fmaxf(pa0.x + qa.x, 0.f);
        z[1] = fmaxf(pa0.y + qa.y, 0.f);
        z[2] = fmaxf(pa0.z + qa.z, 0.f);
        z[3] = fmaxf(pa0.w + qa.w, 0.f);
        z[4] = fmaxf(pb0.x + qb.x, 0.f);
        z[5] = fmaxf(pb0.y + qb.y, 0.f);
        z[6] = fmaxf(pb0.z + qb.z, 0.f);
        z[7] = fmaxf(pb0.w + qb.w, 0.f);
        float o0 = 0.f, o1 = 0.f, o2 = 0.f;
#pragma unroll
        for (int q = 0; q < 8; ++q) {
            o0 += z[q] * w2r[q][0];
            o1 += z[q] * w2r[q][1];
            o2 += z[q] * w2r[q][2];
        }
#pragma unroll
        for (int m = 1; m < 16; m <<= 1) {  // reduce within 16-lane group
            o0 += __shfl_xor(o0, m);
            o1 += __shfl_xor(o1, m);
            o2 += __shfl_xor(o2, m);
        }
        if ((l & 15) == 0) {
            float* op = out + (size_t)c0.y * 3;
            op[0] = o0 + bz0;
            op[1] = o1 + bz1;
            op[2] = o2 + bz2;
        }
        c0 = c1; pa0 = pa1; pb0 = pb1;
        c1 = c2; pa1 = pa2; pb1 = pb2;
    }
}

extern "C" void kernel_launch(void* const* d_in, const int* in_sizes, int n_in,
                              void* d_out, int out_size, void* d_ws, size_t ws_size,
                              hipStream_t stream) {
    const float* x     = (const float*)d_in[0];
    const int*   ei    = (const int*)d_in[1];
    const float* W_enc = (const float*)d_in[2];
    const float* b_enc = (const float*)d_in[3];
    const float* Wg[3] = {(const float*)d_in[4], (const float*)d_in[6], (const float*)d_in[8]};
    const float* bg[3] = {(const float*)d_in[5], (const float*)d_in[7], (const float*)d_in[9]};
    const float* W_m1  = (const float*)d_in[10];
    const float* b_m1  = (const float*)d_in[11];
    const float* W_m2  = (const float*)d_in[12];
    const float* b_m2  = (const float*)d_in[13];
    float* out = (float*)d_out;

    // workspace layout (~87 MB)
    char* w = (char*)d_ws;
    ushort* hH      = (ushort*)w;  w += (size_t)N_NODES * HID * 2;       // 12.8 MB
    ushort* hL      = (ushort*)w;  w += (size_t)N_NODES * HID * 2;       // 12.8 MB
    float*  hB      = (float*)w;   w += (size_t)N_NODES * HID * 4;       // 25.6 MB (hw' / P)
    float*  Qb      = (float*)w;   w += (size_t)N_NODES * HID * 4;       // 25.6 MB (Q + b1)
    int2*   csrE    = (int2*)w;    w += (size_t)N_EDGES * 8;             // 6.4 MB
    int*    csrA    = (int*)w;     w += (size_t)N_EDGES * 4;             // 3.2 MB
    float*  dinv    = (float*)w;   w += (size_t)N_NODES * 4;
    int*    rowStart= (int*)w;     w += (size_t)(N_NODES + 4) * 4;
    int*    cursor  = (int*)w;     w += (size_t)N_NODES * 4;
    int*    blockSums=(int*)w;     w += 512;
    ushort* WgTH[3], *WgTL[3];
    for (int i = 0; i < 3; ++i) {
        WgTH[i] = (ushort*)w; w += 128 * 128 * 2;
        WgTL[i] = (ushort*)w; w += 128 * 128 * 2;
    }
    ushort* WtTH = (ushort*)w; w += 128 * 128 * 2;
    ushort* WtTL = (ushort*)w; w += 128 * 128 * 2;
    ushort* WbTH = (ushort*)w; w += 128 * 128 * 2;
    ushort* WbTL = (ushort*)w; w += 128 * 128 * 2;

    // --- CSR build (once; reused across layers + edge stage) ---
    k_zero_cnt<<<(N_NODES + 255) / 256, 256, 0, stream>>>(cursor);
    k_count<<<(N_EDGES + 255) / 256, 256, 0, stream>>>(ei, cursor);
    k_scan1<<<N_SCAN_BLOCKS, SCAN_BLK, 0, stream>>>(cursor, rowStart, blockSums, dinv);
    k_scan2<<<1, 64, 0, stream>>>(blockSums);
    k_scan3<<<N_SCAN_BLOCKS, SCAN_BLK, 0, stream>>>(rowStart, blockSums, cursor);
    k_fill<<<(N_EDGES + 255) / 256, 256, 0, stream>>>(ei, rowStart, cursor, csrA, csrE);

    // --- all 5 weight transpose+splits in one launch ---
    WSplitArgs wa;
    wa.src[0] = Wg[0]; wa.th[0] = WgTH[0]; wa.tl[0] = WgTL[0];
    wa.src[1] = Wg[1]; wa.th[1] = WgTH[1]; wa.tl[1] = WgTL[1];
    wa.src[2] = Wg[2]; wa.th[2] = WgTH[2]; wa.tl[2] = WgTL[2];
    wa.src[3] = W_m1;             wa.th[3] = WtTH; wa.tl[3] = WtTL;
    wa.src[4] = W_m1 + 128 * 128; wa.th[4] = WbTH; wa.tl[4] = WbTL;
    k_tsplit5<<<5 * 16384 / 256, 256, 0, stream>>>(wa);

    k_encoder<<<N_NODES * 64 / 256, 256, 0, stream>>>(x, W_enc, b_enc, hH, hL);

    const int gemmGrid = (N_NODES + 127) / 128;
    for (int l = 0; l < 3; ++l) {
        // hw' = (relu(h) @ Wg) * dinv[row]
        k_gemm_mfma<<<gemmGrid, 256, 0, stream>>>(hH, hL, WgTH[l], WgTL[l], hB, dinv, N_NODES);
        k_aggregate<<<(N_NODES * 64) / 256, 256, 0, stream>>>(hB, bg[l], dinv, rowStart, csrA, hH, hL);
    }

    // P = relu(h3)@W1_top ; Qb = relu(h3)@W1_bot + b1  (one dispatch, blockIdx.y)
    dim3 pqGrid(gemmGrid, 2);
    k_gemm_pq<<<pqGrid, 256, 0, stream>>>(hH, hL, WtTH, WtTL, WbTH, WbTL, hB, Qb, b_m1, N_NODES);

    k_edge_final<<<(N_NODES * 64) / 256, 256, 0, stream>>>(hB, Qb, rowStart, csrE, W_m2, b_m2, out);
}

// Round 9
// 469.342 us; speedup vs baseline: 1.8964x; 1.0767x over previous
//
#include <hip/hip_runtime.h>
#include <hip/hip_bf16.h>

#define N_NODES 50000
#define N_EDGES 800000
#define HID 128
#define SCAN_BLK 512
#define N_SCAN_BLOCKS ((N_NODES + SCAN_BLK - 1) / SCAN_BLK)  // 98

typedef __attribute__((ext_vector_type(8))) short bf16x8;
typedef __attribute__((ext_vector_type(4))) float f32x4;

__device__ __forceinline__ ushort f2bf(float f) {
    uint u = __float_as_uint(f);
    return (ushort)((u + 0x7FFFu + ((u >> 16) & 1u)) >> 16);  // RNE
}
__device__ __forceinline__ float bf2f(ushort h) { return __uint_as_float(((uint)h) << 16); }

// ---------------- CSR build ----------------
__global__ void k_count(const int* __restrict__ ei, int* cnt) {
    int e = blockIdx.x * blockDim.x + threadIdx.x;
    if (e < N_EDGES) atomicAdd(&cnt[ei[N_EDGES + e]], 1);
}

__global__ __launch_bounds__(SCAN_BLK) void k_scan1(const int* __restrict__ cnt,
                                                    int* __restrict__ rowStart,
                                                    int* __restrict__ blockSums,
                                                    float* __restrict__ dinv) {
    __shared__ int tmp[SCAN_BLK];
    int i = blockIdx.x * SCAN_BLK + threadIdx.x;
    int v = (i < N_NODES) ? cnt[i] : 0;
    if (i < N_NODES) dinv[i] = rsqrtf(1.0f + (float)v);
    tmp[threadIdx.x] = v;
    __syncthreads();
    for (int off = 1; off < SCAN_BLK; off <<= 1) {
        int t = (threadIdx.x >= off) ? tmp[threadIdx.x - off] : 0;
        __syncthreads();
        tmp[threadIdx.x] += t;
        __syncthreads();
    }
    if (i < N_NODES) rowStart[i] = tmp[threadIdx.x] - v;  // exclusive (within block)
    if (threadIdx.x == SCAN_BLK - 1) blockSums[blockIdx.x] = tmp[SCAN_BLK - 1];
}

// fused scan2+scan3: every block redundantly prefix-sums the 98 block sums in LDS.
__global__ __launch_bounds__(SCAN_BLK) void k_scan23(int* __restrict__ rowStart,
                                                     const int* __restrict__ blockSums,
                                                     int* __restrict__ cursor) {
    __shared__ int ps[128];
    int t = threadIdx.x;
    if (t < 128) ps[t] = (t < N_SCAN_BLOCKS) ? blockSums[t] : 0;
    __syncthreads();
    for (int off = 1; off < 128; off <<= 1) {
        int v = (t < 128 && t >= off) ? ps[t - off] : 0;
        __syncthreads();
        if (t < 128) ps[t] += v;
        __syncthreads();
    }
    int i = blockIdx.x * SCAN_BLK + t;
    int prefix = (blockIdx.x == 0) ? 0 : ps[blockIdx.x - 1];
    if (i < N_NODES) {
        rowStart[i] += prefix;
        cursor[i] = 0;
    }
    if (i == 0) rowStart[N_NODES] = N_EDGES;
}

// csrE[pos] = {src, edge_id}
__global__ void k_fill(const int* __restrict__ ei, const int* __restrict__ rowStart,
                       int* cursor, int2* __restrict__ csrE) {
    int e = blockIdx.x * blockDim.x + threadIdx.x;
    if (e < N_EDGES) {
        int s = ei[e];
        int d = ei[N_EDGES + e];
        int pos = rowStart[d] + atomicAdd(&cursor[d], 1);
        csrE[pos] = make_int2(s, e);
    }
}

// ---------------- 5x weight transpose + bf16 hi/lo split: T[j][k] = split(W[k][j]) ----------------
struct WSplitArgs {
    const float* src[5];
    ushort* th[5];
    ushort* tl[5];
};

__global__ void k_tsplit5(WSplitArgs a) {
    int i = blockIdx.x * 256 + threadIdx.x;  // 5 * 16384
    int which = i >> 14, r = i & 16383;
    int k = r >> 7, j = r & 127;
    float v = a.src[which][r];
    ushort hi = f2bf(v);
    a.th[which][j * 128 + k] = hi;
    a.tl[which][j * 128 + k] = f2bf(v - bf2f(hi));
}

// ---------------- encoder: h0 = relu(x @ W_enc + b), stored as bf16 hi/lo split ----------------
__global__ void k_encoder(const float* __restrict__ x, const float* __restrict__ W,
                          const float* __restrict__ b, ushort* __restrict__ hH,
                          ushort* __restrict__ hL) {
    int i = blockIdx.x * 256 + threadIdx.x;  // N*64 threads, 2 cols each
    int n = i >> 6, l = i & 63;
    int j = l * 2;
    float4 xv = *(const float4*)(x + (size_t)n * 4);
    float2 acc = *(const float2*)(b + j);
    float2 w0 = *(const float2*)(W + 0 * 128 + j);
    float2 w1 = *(const float2*)(W + 1 * 128 + j);
    float2 w2 = *(const float2*)(W + 2 * 128 + j);
    float2 w3 = *(const float2*)(W + 3 * 128 + j);
    acc.x += xv.x * w0.x + xv.y * w1.x + xv.z * w2.x + xv.w * w3.x;
    acc.y += xv.x * w0.y + xv.y * w1.y + xv.z * w2.y + xv.w * w3.y;
    float v0 = fmaxf(acc.x, 0.f), v1 = fmaxf(acc.y, 0.f);
    ushort h0 = f2bf(v0), h1 = f2bf(v1);
    ushort l0 = f2bf(v0 - bf2f(h0)), l1 = f2bf(v1 - bf2f(h1));
    ((uint*)hH)[i] = (uint)h0 | ((uint)h1 << 16);
    ((uint*)hL)[i] = (uint)l0 | ((uint)l1 << 16);
}

// ---------------- MFMA GEMM body: out[M,128] = A @ BT^T (+bias) (*scale) ----------------
// Swapped operands: mfma(W_frag, h_frag) -> D col = node (lane&15), row = j -> float4 stores.
__device__ __forceinline__ void gemm_body(const ushort* __restrict__ AH,
                                          const ushort* __restrict__ AL,
                                          const ushort* __restrict__ BTH,
                                          const ushort* __restrict__ BTL,
                                          float* __restrict__ out,
                                          const float* __restrict__ bias,
                                          const float* __restrict__ scale, int M) {
    int tid = threadIdx.x;
    int w = tid >> 6, l = tid & 63;
    int ln = l & 15, lk = l >> 4;
    int r0 = blockIdx.x * 128 + w * 32;      // wave covers 32 rows (2 node-tiles)
    int row0 = r0 + ln, row1 = r0 + 16 + ln;
    int a0 = row0 < M ? row0 : M - 1;
    int a1 = row1 < M ? row1 : M - 1;

    f32x4 acc0[8] = {};
    f32x4 acc1[8] = {};
#pragma unroll
    for (int kc = 0; kc < 4; ++kc) {
        int ko = kc * 32 + lk * 8;
        bf16x8 h0H = *(const bf16x8*)(AH + (size_t)a0 * 128 + ko);
        bf16x8 h0L = *(const bf16x8*)(AL + (size_t)a0 * 128 + ko);
        bf16x8 h1H = *(const bf16x8*)(AH + (size_t)a1 * 128 + ko);
        bf16x8 h1L = *(const bf16x8*)(AL + (size_t)a1 * 128 + ko);
#pragma unroll
        for (int nt = 0; nt < 8; ++nt) {
            size_t boff = (size_t)(nt * 16 + ln) * 128 + ko;
            bf16x8 wH = *(const bf16x8*)(BTH + boff);
            bf16x8 wL = *(const bf16x8*)(BTL + boff);
            acc0[nt] = __builtin_amdgcn_mfma_f32_16x16x32_bf16(wH, h0H, acc0[nt], 0, 0, 0);
            acc0[nt] = __builtin_amdgcn_mfma_f32_16x16x32_bf16(wL, h0H, acc0[nt], 0, 0, 0);
            acc0[nt] = __builtin_amdgcn_mfma_f32_16x16x32_bf16(wH, h0L, acc0[nt], 0, 0, 0);
            acc1[nt] = __builtin_amdgcn_mfma_f32_16x16x32_bf16(wH, h1H, acc1[nt], 0, 0, 0);
            acc1[nt] = __builtin_amdgcn_mfma_f32_16x16x32_bf16(wL, h1H, acc1[nt], 0, 0, 0);
            acc1[nt] = __builtin_amdgcn_mfma_f32_16x16x32_bf16(wH, h1L, acc1[nt], 0, 0, 0);
        }
    }
    float s0v = scale ? scale[a0] : 1.f;
    float s1v = scale ? scale[a1] : 1.f;
#pragma unroll
    for (int nt = 0; nt < 8; ++nt) {
        int jb = nt * 16 + lk * 4;
        float4 bv;
        if (bias) bv = *(const float4*)(bias + jb);
        else bv = make_float4(0.f, 0.f, 0.f, 0.f);
        if (row0 < M) {
            float4 o = make_float4((acc0[nt][0] + bv.x) * s0v, (acc0[nt][1] + bv.y) * s0v,
                                   (acc0[nt][2] + bv.z) * s0v, (acc0[nt][3] + bv.w) * s0v);
            *(float4*)(out + (size_t)row0 * 128 + jb) = o;
        }
        if (row1 < M) {
            float4 o = make_float4((acc1[nt][0] + bv.x) * s1v, (acc1[nt][1] + bv.y) * s1v,
                                   (acc1[nt][2] + bv.z) * s1v, (acc1[nt][3] + bv.w) * s1v);
            *(float4*)(out + (size_t)row1 * 128 + jb) = o;
        }
    }
}

__global__ __launch_bounds__(256) void k_gemm_mfma(const ushort* __restrict__ AH,
                                                   const ushort* __restrict__ AL,
                                                   const ushort* __restrict__ BTH,
                                                   const ushort* __restrict__ BTL,
                                                   float* __restrict__ out,
                                                   const float* __restrict__ scale, int M) {
    gemm_body(AH, AL, BTH, BTL, out, nullptr, scale, M);
}

// P and Q in one dispatch: blockIdx.y selects weight/output set.
__global__ __launch_bounds__(256) void k_gemm_pq(const ushort* __restrict__ AH,
                                                 const ushort* __restrict__ AL,
                                                 const ushort* __restrict__ BTHt,
                                                 const ushort* __restrict__ BTLt,
                                                 const ushort* __restrict__ BTHb,
                                                 const ushort* __restrict__ BTLb,
                                                 float* __restrict__ outP,
                                                 float* __restrict__ outQ,
                                                 const float* __restrict__ b1, int M) {
    if (blockIdx.y == 0)
        gemm_body(AH, AL, BTHt, BTLt, outP, nullptr, nullptr, M);
    else
        gemm_body(AH, AL, BTHb, BTLb, outQ, b1, nullptr, M);
}

// ---------------- aggregate: h = relu(b + dinv[n]*(hw'[n] + sum hw'[src])) ----------------
// hw' rows pre-scaled by dinv[src]. One wave per node; 4 groups x 16 lanes, each group
// covers the full 512B row (2 x float4/lane), 4 edges concurrently, 1-ahead prefetch.
__global__ __launch_bounds__(256) void k_aggregate(const float* __restrict__ hw,
                                                   const float* __restrict__ b,
                                                   const float* __restrict__ dinv,
                                                   const int* __restrict__ rowStart,
                                                   const int2* __restrict__ csrE,
                                                   ushort* __restrict__ hH,
                                                   ushort* __restrict__ hL) {
    int wid = (blockIdx.x * 256 + threadIdx.x) >> 6;  // one wave per node
    int l = threadIdx.x & 63;
    if (wid >= N_NODES) return;
    int g = l >> 4, li = l & 15;
    int c8 = li * 8;

    float4 aA, aB;
    if (g == 0) {  // self term
        aA = *(const float4*)(hw + (size_t)wid * 128 + c8);
        aB = *(const float4*)(hw + (size_t)wid * 128 + c8 + 4);
    } else {
        aA = make_float4(0.f, 0.f, 0.f, 0.f);
        aB = aA;
    }

    int s0 = rowStart[wid], s1 = rowStart[wid + 1];
    int k = s0 + g;
    float4 v0a = make_float4(0.f, 0.f, 0.f, 0.f), v0b = v0a;
    if (k < s1) {
        const float* r = hw + (size_t)csrE[k].x * 128 + c8;
        v0a = *(const float4*)(r);
        v0b = *(const float4*)(r + 4);
    }
    for (; k < s1; k += 4) {
        float4 v1a = make_float4(0.f, 0.f, 0.f, 0.f), v1b = v1a;
        if (k + 4 < s1) {
            const float* r = hw + (size_t)csrE[k + 4].x * 128 + c8;
            v1a = *(const float4*)(r);
            v1b = *(const float4*)(r + 4);
        }
        aA.x += v0a.x; aA.y += v0a.y; aA.z += v0a.z; aA.w += v0a.w;
        aB.x += v0b.x; aB.y += v0b.y; aB.z += v0b.z; aB.w += v0b.w;
        v0a = v1a;
        v0b = v1b;
    }
    // combine the 4 groups (same columns in each group)
    aA.x += __shfl_xor(aA.x, 16); aA.y += __shfl_xor(aA.y, 16);
    aA.z += __shfl_xor(aA.z, 16); aA.w += __shfl_xor(aA.w, 16);
    aB.x += __shfl_xor(aB.x, 16); aB.y += __shfl_xor(aB.y, 16);
    aB.z += __shfl_xor(aB.z, 16); aB.w += __shfl_xor(aB.w, 16);
    aA.x += __shfl_xor(aA.x, 32); aA.y += __shfl_xor(aA.y, 32);
    aA.z += __shfl_xor(aA.z, 32); aA.w += __shfl_xor(aA.w, 32);
    aB.x += __shfl_xor(aB.x, 32); aB.y += __shfl_xor(aB.y, 32);
    aB.z += __shfl_xor(aB.z, 32); aB.w += __shfl_xor(aB.w, 32);

    if (g == 0) {
        float di = dinv[wid];
        float4 bbA = *(const float4*)(b + c8);
        float4 bbB = *(const float4*)(b + c8 + 4);
        float f0 = fmaxf(bbA.x + di * aA.x, 0.f);
        float f1 = fmaxf(bbA.y + di * aA.y, 0.f);
        float f2 = fmaxf(bbA.z + di * aA.z, 0.f);
        float f3 = fmaxf(bbA.w + di * aA.w, 0.f);
        float f4v = fmaxf(bbB.x + di * aB.x, 0.f);
        float f5 = fmaxf(bbB.y + di * aB.y, 0.f);
        float f6 = fmaxf(bbB.z + di * aB.z, 0.f);
        float f7 = fmaxf(bbB.w + di * aB.w, 0.f);
        ushort h0 = f2bf(f0), h1 = f2bf(f1), h2 = f2bf(f2), h3 = f2bf(f3);
        ushort h4 = f2bf(f4v), h5 = f2bf(f5), h6 = f2bf(f6), h7 = f2bf(f7);
        uint4 uh = make_uint4((uint)h0 | ((uint)h1 << 16), (uint)h2 | ((uint)h3 << 16),
                              (uint)h4 | ((uint)h5 << 16), (uint)h6 | ((uint)h7 << 16));
        ushort l0 = f2bf(f0 - bf2f(h0)), l1 = f2bf(f1 - bf2f(h1));
        ushort l2 = f2bf(f2 - bf2f(h2)), l3 = f2bf(f3 - bf2f(h3));
        ushort l4 = f2bf(f4v - bf2f(h4)), l5 = f2bf(f5 - bf2f(h5));
        ushort l6 = f2bf(f6 - bf2f(h6)), l7 = f2bf(f7 - bf2f(h7));
        uint4 ul = make_uint4((uint)l0 | ((uint)l1 << 16), (uint)l2 | ((uint)l3 << 16),
                              (uint)l4 | ((uint)l5 << 16), (uint)l6 | ((uint)l7 << 16));
        *(uint4*)(hH + (size_t)wid * 128 + c8) = uh;
        *(uint4*)(hL + (size_t)wid * 128 + c8) = ul;
    }
}

// ---------------- edge final: out[eid] = relu(P[src] + Qb[dst]) @ W2 + b2 ----------------
// One wave per dst node; Qb (= Q + b1) in registers. 4 groups of 16 lanes process
// 4 edges concurrently, software-pipelined one edge ahead.
__global__ __launch_bounds__(256) void k_edge_final(const float* __restrict__ P,
                                                    const float* __restrict__ Qb,
                                                    const int* __restrict__ rowStart,
                                                    const int2* __restrict__ csrE,
                                                    const float* __restrict__ W2,
                                                    const float* __restrict__ b2,
                                                    float* __restrict__ out) {
    int wid = (blockIdx.x * 256 + threadIdx.x) >> 6;  // one wave per dst node
    int l = threadIdx.x & 63;
    if (wid >= N_NODES) return;
    int s0 = rowStart[wid], s1 = rowStart[wid + 1];
    if (s0 >= s1) return;
    int j8 = (l & 15) * 8;  // my 8 columns
    int g = l >> 4;         // edge-slot within wave

    float4 qa = *(const float4*)(Qb + (size_t)wid * 128 + j8);
    float4 qb = *(const float4*)(Qb + (size_t)wid * 128 + j8 + 4);
    float w2r[8][3];
#pragma unroll
    for (int k = 0; k < 8; ++k) {
        w2r[k][0] = W2[(j8 + k) * 3 + 0];
        w2r[k][1] = W2[(j8 + k) * 3 + 1];
        w2r[k][2] = W2[(j8 + k) * 3 + 2];
    }
    float bz0 = b2[0], bz1 = b2[1], bz2 = b2[2];

    int k = s0 + g;
    int2 c = make_int2(0, 0);
    float4 pa = make_float4(0.f, 0.f, 0.f, 0.f), pb = pa;
    if (k < s1) {
        c = csrE[k];
        const float* pr = P + (size_t)c.x * 128 + j8;
        pa = *(const float4*)(pr);
        pb = *(const float4*)(pr + 4);
    }
    for (; k < s1; k += 4) {
        int kn = k + 4;
        int2 cn = make_int2(0, 0);
        float4 pan = make_float4(0.f, 0.f, 0.f, 0.f), pbn = pan;
        if (kn < s1) {
            cn = csrE[kn];
            const float* prn = P + (size_t)cn.x * 128 + j8;
            pan = *(const float4*)(prn);
            pbn = *(const float4*)(prn + 4);
        }
        float z[8];
        z[0] = fmaxf(pa.x + qa.x, 0.f);
        z[1] = fmaxf(pa.y + qa.y, 0.f);
        z[2] = fmaxf(pa.z + qa.z, 0.f);
        z[3] = fmaxf(pa.w + qa.w, 0.f);
        z[4] = fmaxf(pb.x + qb.x, 0.f);
        z[5] = fmaxf(pb.y + qb.y, 0.f);
        z[6] = fmaxf(pb.z + qb.z, 0.f);
        z[7] = fmaxf(pb.w + qb.w, 0.f);
        float o0 = 0.f, o1 = 0.f, o2 = 0.f;
#pragma unroll
        for (int q = 0; q < 8; ++q) {
            o0 += z[q] * w2r[q][0];
            o1 += z[q] * w2r[q][1];
            o2 += z[q] * w2r[q][2];
        }
#pragma unroll
        for (int m = 1; m < 16; m <<= 1) {  // reduce within 16-lane group
            o0 += __shfl_xor(o0, m);
            o1 += __shfl_xor(o1, m);
            o2 += __shfl_xor(o2, m);
        }
        if ((l & 15) == 0) {
            float* op = out + (size_t)c.y * 3;
            op[0] = o0 + bz0;
            op[1] = o1 + bz1;
            op[2] = o2 + bz2;
        }
        c = cn;
        pa = pan;
        pb = pbn;
    }
}

extern "C" void kernel_launch(void* const* d_in, const int* in_sizes, int n_in,
                              void* d_out, int out_size, void* d_ws, size_t ws_size,
                              hipStream_t stream) {
    const float* x     = (const float*)d_in[0];
    const int*   ei    = (const int*)d_in[1];
    const float* W_enc = (const float*)d_in[2];
    const float* b_enc = (const float*)d_in[3];
    const float* Wg[3] = {(const float*)d_in[4], (const float*)d_in[6], (const float*)d_in[8]};
    const float* bg[3] = {(const float*)d_in[5], (const float*)d_in[7], (const float*)d_in[9]};
    const float* W_m1  = (const float*)d_in[10];
    const float* b_m1  = (const float*)d_in[11];
    const float* W_m2  = (const float*)d_in[12];
    const float* b_m2  = (const float*)d_in[13];
    float* out = (float*)d_out;

    // workspace layout (~84 MB)
    char* w = (char*)d_ws;
    ushort* hH      = (ushort*)w;  w += (size_t)N_NODES * HID * 2;       // 12.8 MB
    ushort* hL      = (ushort*)w;  w += (size_t)N_NODES * HID * 2;       // 12.8 MB
    float*  hB      = (float*)w;   w += (size_t)N_NODES * HID * 4;       // 25.6 MB (hw' / P)
    float*  Qb      = (float*)w;   w += (size_t)N_NODES * HID * 4;       // 25.6 MB (Q + b1)
    int2*   csrE    = (int2*)w;    w += (size_t)N_EDGES * 8;             // 6.4 MB
    float*  dinv    = (float*)w;   w += (size_t)N_NODES * 4;
    int*    rowStart= (int*)w;     w += (size_t)(N_NODES + 4) * 4;
    int*    cursor  = (int*)w;     w += (size_t)N_NODES * 4;
    int*    blockSums=(int*)w;     w += 512;
    ushort* WgTH[3], *WgTL[3];
    for (int i = 0; i < 3; ++i) {
        WgTH[i] = (ushort*)w; w += 128 * 128 * 2;
        WgTL[i] = (ushort*)w; w += 128 * 128 * 2;
    }
    ushort* WtTH = (ushort*)w; w += 128 * 128 * 2;
    ushort* WtTL = (ushort*)w; w += 128 * 128 * 2;
    ushort* WbTH = (ushort*)w; w += 128 * 128 * 2;
    ushort* WbTL = (ushort*)w; w += 128 * 128 * 2;

    // --- CSR build (once; reused across layers + edge stage) ---
    hipMemsetAsync(cursor, 0, (size_t)N_NODES * 4, stream);
    k_count<<<(N_EDGES + 255) / 256, 256, 0, stream>>>(ei, cursor);
    k_scan1<<<N_SCAN_BLOCKS, SCAN_BLK, 0, stream>>>(cursor, rowStart, blockSums, dinv);
    k_scan23<<<N_SCAN_BLOCKS, SCAN_BLK, 0, stream>>>(rowStart, blockSums, cursor);
    k_fill<<<(N_EDGES + 255) / 256, 256, 0, stream>>>(ei, rowStart, cursor, csrE);

    // --- all 5 weight transpose+splits in one launch ---
    WSplitArgs wa;
    wa.src[0] = Wg[0]; wa.th[0] = WgTH[0]; wa.tl[0] = WgTL[0];
    wa.src[1] = Wg[1]; wa.th[1] = WgTH[1]; wa.tl[1] = WgTL[1];
    wa.src[2] = Wg[2]; wa.th[2] = WgTH[2]; wa.tl[2] = WgTL[2];
    wa.src[3] = W_m1;             wa.th[3] = WtTH; wa.tl[3] = WtTL;
    wa.src[4] = W_m1 + 128 * 128; wa.th[4] = WbTH; wa.tl[4] = WbTL;
    k_tsplit5<<<5 * 16384 / 256, 256, 0, stream>>>(wa);

    k_encoder<<<N_NODES * 64 / 256, 256, 0, stream>>>(x, W_enc, b_enc, hH, hL);

    const int gemmGrid = (N_NODES + 127) / 128;
    for (int l = 0; l < 3; ++l) {
        // hw' = (relu(h) @ Wg) * dinv[row]
        k_gemm_mfma<<<gemmGrid, 256, 0, stream>>>(hH, hL, WgTH[l], WgTL[l], hB, dinv, N_NODES);
        k_aggregate<<<(N_NODES * 64) / 256, 256, 0, stream>>>(hB, bg[l], dinv, rowStart, csrE, hH, hL);
    }

    // P = relu(h3)@W1_top ; Qb = relu(h3)@W1_bot + b1  (one dispatch, blockIdx.y)
    dim3 pqGrid(gemmGrid, 2);
    k_gemm_pq<<<pqGrid, 256, 0, stream>>>(hH, hL, WtTH, WtTL, WbTH, WbTL, hB, Qb, b_m1, N_NODES);

    k_edge_final<<<(N_NODES * 64) / 256, 256, 0, stream>>>(hB, Qb, rowStart, csrE, W_m2, b_m2, out);
}